// Round 1
// baseline (245.378 us; speedup 1.0000x reference)
//
#include <hip/hip_runtime.h>
#include <math.h>

// Problem constants (from reference): B=8192, N=49, D=3, D3=42, E=128, K=3
#define N_   49
#define D3_  42
#define E_   128

// ---------------------------------------------------------------------------
// Precompute kernel: collapse the feature-pipeline + final matmul to rank-2.
//   out[b,n,e] = cd[b,n]*U[e] + den[b,n]*V[e] + C[e]
// U, V, C are 128-vectors, stored in d_ws as [U | V | C].
// ---------------------------------------------------------------------------
__global__ void precompute_uvc(const float* __restrict__ W_dist,
                               const float* __restrict__ b_dist,
                               const float* __restrict__ emb,
                               const float* __restrict__ W_den,
                               const float* __restrict__ b_den,
                               const float* __restrict__ W_out,
                               const float* __restrict__ b_out,
                               float* __restrict__ uvc) {
    int e = threadIdx.x;
    if (e >= E_) return;
    const float* embN = emb + N_ * D3_;  // emb[49] row (n_valid == N == 49)
    float u = 0.f, v = 0.f, c = b_out[e];
    for (int j = 0; j < D3_; ++j) {
        float w0 = W_out[j * E_ + e];              // dist block
        float w1 = W_out[(D3_ + j) * E_ + e];      // count block
        float w2 = W_out[(2 * D3_ + j) * E_ + e];  // density block
        u = fmaf(W_dist[j], w0, u);
        v = fmaf(W_den[j], w2, v);
        c = fmaf(b_dist[j], w0, c);
        c = fmaf(embN[j], w1, c);
        c = fmaf(b_den[j], w2, c);
    }
    uvc[e]          = u;
    uvc[E_ + e]     = v;
    uvc[2 * E_ + e] = c;
}

// ---------------------------------------------------------------------------
// Main kernel: one block per batch element.
//   Phase 1: stage points (147 f32) + U/V/C (384 f32) into LDS
//   Phase 2: centroid (3 threads), then lanes n<49 compute cd[n] and
//            den[n] = mean of 3 smallest neighbor distances (insertion top-3
//            on squared distances; sqrt applied at the end — monotone, exact)
//   Phase 3: all 256 threads write 49*128 f32 as float4 (coalesced:
//            each half-wave emits one contiguous 512 B output row)
// ---------------------------------------------------------------------------
__global__ __launch_bounds__(256) void rank2_feature_kernel(
        const float* __restrict__ points,
        const float* __restrict__ uvc,
        float* __restrict__ out) {
    __shared__ float pts[N_ * 3];
    __shared__ __align__(16) float sU[E_];
    __shared__ __align__(16) float sV[E_];
    __shared__ __align__(16) float sC[E_];
    __shared__ float cent[3];
    __shared__ float cd[N_];
    __shared__ float den[N_];

    const int tid = threadIdx.x;
    const long long b = blockIdx.x;
    const float* pb = points + b * (N_ * 3);

    if (tid < N_ * 3) pts[tid] = pb[tid];
    if (tid < E_) {
        sU[tid] = uvc[tid];
        sV[tid] = uvc[E_ + tid];
        sC[tid] = uvc[2 * E_ + tid];
    }
    __syncthreads();

    // centroid: 3 threads, one per coordinate
    if (tid < 3) {
        float s = 0.f;
        for (int i = 0; i < N_; ++i) s += pts[3 * i + tid];
        cent[tid] = s * (1.0f / N_);
    }
    __syncthreads();

    // per-point features: lanes 0..48 of wave 0
    if (tid < N_) {
        const int n = tid;
        const float px = pts[3 * n], py = pts[3 * n + 1], pz = pts[3 * n + 2];

        // centroid distance
        {
            float dx = px - cent[0], dy = py - cent[1], dz = pz - cent[2];
            cd[n] = sqrtf(dx * dx + dy * dy + dz * dz);
        }

        // 3 smallest squared distances to other points (LDS broadcast reads:
        // all lanes read the same pts[m] each iteration -> conflict-free)
        float s0 = INFINITY, s1 = INFINITY, s2 = INFINITY;
        for (int m = 0; m < N_; ++m) {
            float dx = px - pts[3 * m];
            float dy = py - pts[3 * m + 1];
            float dz = pz - pts[3 * m + 2];
            float d2 = dx * dx + dy * dy + dz * dz;
            if (m != n) {
                if (d2 < s0)      { s2 = s1; s1 = s0; s0 = d2; }
                else if (d2 < s1) { s2 = s1; s1 = d2; }
                else if (d2 < s2) { s2 = d2; }
            }
        }
        den[n] = (sqrtf(s0) + sqrtf(s1) + sqrtf(s2)) * (1.0f / 3.0f);
    }
    __syncthreads();

    // rank-2 broadcast write: 49 rows x 32 float4 = 1568 float4 stores/block
    const float4* u4 = (const float4*)sU;
    const float4* v4 = (const float4*)sV;
    const float4* c4 = (const float4*)sC;
    float* outb = out + b * (long long)(N_ * E_);
    for (int i = tid; i < N_ * (E_ / 4); i += 256) {
        int n = i >> 5;       // row
        int q = i & 31;       // float4 index within row
        float a = cd[n];
        float d = den[n];
        float4 u = u4[q], v = v4[q], c = c4[q];
        float4 r;
        r.x = fmaf(a, u.x, fmaf(d, v.x, c.x));
        r.y = fmaf(a, u.y, fmaf(d, v.y, c.y));
        r.z = fmaf(a, u.z, fmaf(d, v.z, c.z));
        r.w = fmaf(a, u.w, fmaf(d, v.w, c.w));
        ((float4*)(outb + n * E_))[q] = r;
    }
}

extern "C" void kernel_launch(void* const* d_in, const int* in_sizes, int n_in,
                              void* d_out, int out_size, void* d_ws, size_t ws_size,
                              hipStream_t stream) {
    const float* points = (const float*)d_in[0];
    const float* W_dist = (const float*)d_in[1];
    const float* b_dist = (const float*)d_in[2];
    const float* emb    = (const float*)d_in[3];
    const float* W_den  = (const float*)d_in[4];
    const float* b_den  = (const float*)d_in[5];
    const float* W_out  = (const float*)d_in[6];
    const float* b_out  = (const float*)d_in[7];
    float* out = (float*)d_out;
    float* uvc = (float*)d_ws;  // 3*128 floats = 1536 B scratch

    int B = in_sizes[0] / (N_ * 3);

    precompute_uvc<<<1, 128, 0, stream>>>(W_dist, b_dist, emb, W_den, b_den,
                                          W_out, b_out, uvc);
    rank2_feature_kernel<<<B, 256, 0, stream>>>(points, uvc, out);
}

// Round 2
// 238.457 us; speedup vs baseline: 1.0290x; 1.0290x over previous
//
#include <hip/hip_runtime.h>
#include <math.h>

// Problem constants (from reference): B=8192, N=49, D=3, D3=42, E=128, K=3
#define N_   49
#define D3_  42
#define E_   128

// d_ws layout: [ uvc: 3*128 f32 (1536 B) | cdden: B*49 float2 (3.2 MB) ]

// ---------------------------------------------------------------------------
// Precompute kernel: collapse the feature-pipeline + final matmul to rank-2.
//   out[b,n,e] = cd[b,n]*U[e] + den[b,n]*V[e] + C[e]
// ---------------------------------------------------------------------------
__global__ void precompute_uvc(const float* __restrict__ W_dist,
                               const float* __restrict__ b_dist,
                               const float* __restrict__ emb,
                               const float* __restrict__ W_den,
                               const float* __restrict__ b_den,
                               const float* __restrict__ W_out,
                               const float* __restrict__ b_out,
                               float* __restrict__ uvc) {
    int e = threadIdx.x;
    if (e >= E_) return;
    const float* embN = emb + N_ * D3_;  // emb[49] row (n_valid == N == 49)
    float u = 0.f, v = 0.f, c = b_out[e];
    for (int j = 0; j < D3_; ++j) {
        float w0 = W_out[j * E_ + e];              // dist block
        float w1 = W_out[(D3_ + j) * E_ + e];      // count block
        float w2 = W_out[(2 * D3_ + j) * E_ + e];  // density block
        u = fmaf(W_dist[j], w0, u);
        v = fmaf(W_den[j], w2, v);
        c = fmaf(b_dist[j], w0, c);
        c = fmaf(embN[j], w1, c);
        c = fmaf(b_den[j], w2, c);
    }
    uvc[e]          = u;
    uvc[E_ + e]     = v;
    uvc[2 * E_ + e] = c;
}

// ---------------------------------------------------------------------------
// Kernel A: per-(batch,point) scalars. One wave (64 threads) per batch.
// Centroid sum is folded into the same 49-iteration loop as the kNN scan.
// Writes cd/den as float2 -> 8 B per point, 3.2 MB total.
// ---------------------------------------------------------------------------
__global__ __launch_bounds__(64) void compute_cdden(
        const float* __restrict__ points,
        float2* __restrict__ cdden) {
    __shared__ float pts[N_ * 3];
    const int tid = threadIdx.x;
    const long long b = blockIdx.x;
    const float* pb = points + b * (N_ * 3);

    for (int i = tid; i < N_ * 3; i += 64) pts[i] = pb[i];
    __syncthreads();

    if (tid < N_) {
        const float px = pts[3 * tid], py = pts[3 * tid + 1], pz = pts[3 * tid + 2];
        float sx = 0.f, sy = 0.f, sz = 0.f;
        float s0 = INFINITY, s1 = INFINITY, s2 = INFINITY;
        for (int m = 0; m < N_; ++m) {
            // all lanes read the same LDS address -> broadcast, conflict-free
            float qx = pts[3 * m], qy = pts[3 * m + 1], qz = pts[3 * m + 2];
            sx += qx; sy += qy; sz += qz;
            float dx = px - qx, dy = py - qy, dz = pz - qz;
            float d2 = fmaf(dx, dx, fmaf(dy, dy, dz * dz));
            if (m != tid) {  // top-3 smallest squared distances (monotone vs sqrt)
                if (d2 < s0)      { s2 = s1; s1 = s0; s0 = d2; }
                else if (d2 < s1) { s2 = s1; s1 = d2; }
                else if (d2 < s2) { s2 = d2; }
            }
        }
        const float inv = 1.0f / (float)N_;
        float cx = sx * inv, cy = sy * inv, cz = sz * inv;
        float dx = px - cx, dy = py - cy, dz = pz - cz;
        float cd  = sqrtf(fmaf(dx, dx, fmaf(dy, dy, dz * dz)));
        float den = (sqrtf(s0) + sqrtf(s1) + sqrtf(s2)) * (1.0f / 3.0f);
        cdden[b * N_ + tid] = make_float2(cd, den);
    }
}

// ---------------------------------------------------------------------------
// Kernel B: pure streaming rank-2 write.
//   out4[r*32 + q] = cd[r]*U4[q] + den[r]*V4[q] + C4[q]
// Each thread owns a fixed q (tid&31) -> U/V/C are loop-invariant registers.
// A 32-lane group emits one contiguous 512 B row per iteration; a wave emits
// 1 KiB contiguous. No LDS, no barriers -> uninterrupted store stream.
// ---------------------------------------------------------------------------
__global__ __launch_bounds__(256) void rank2_write(
        const float2* __restrict__ cdden,
        const float4* __restrict__ uvc4,
        float4* __restrict__ out4,
        int total_rows) {
    const int q   = threadIdx.x & 31;
    const int sub = threadIdx.x >> 5;  // 0..7 row-group within block
    const float4 u = uvc4[q];
    const float4 v = uvc4[32 + q];
    const float4 c = uvc4[64 + q];
    const long long stride = (long long)gridDim.x * 8;
    for (long long r = (long long)blockIdx.x * 8 + sub; r < total_rows; r += stride) {
        float2 ad = cdden[r];           // same addr across 32 lanes -> broadcast
        float4 w;
        w.x = fmaf(ad.x, u.x, fmaf(ad.y, v.x, c.x));
        w.y = fmaf(ad.x, u.y, fmaf(ad.y, v.y, c.y));
        w.z = fmaf(ad.x, u.z, fmaf(ad.y, v.z, c.z));
        w.w = fmaf(ad.x, u.w, fmaf(ad.y, v.w, c.w));
        out4[r * 32 + q] = w;
    }
}

extern "C" void kernel_launch(void* const* d_in, const int* in_sizes, int n_in,
                              void* d_out, int out_size, void* d_ws, size_t ws_size,
                              hipStream_t stream) {
    const float* points = (const float*)d_in[0];
    const float* W_dist = (const float*)d_in[1];
    const float* b_dist = (const float*)d_in[2];
    const float* emb    = (const float*)d_in[3];
    const float* W_den  = (const float*)d_in[4];
    const float* b_den  = (const float*)d_in[5];
    const float* W_out  = (const float*)d_in[6];
    const float* b_out  = (const float*)d_in[7];

    float*  uvc   = (float*)d_ws;                       // 384 f32 = 1536 B
    float2* cdden = (float2*)((char*)d_ws + 1536);      // B*49 float2

    const int B = in_sizes[0] / (N_ * 3);
    const int total_rows = B * N_;

    precompute_uvc<<<1, 128, 0, stream>>>(W_dist, b_dist, emb, W_den, b_den,
                                          W_out, b_out, uvc);
    compute_cdden<<<B, 64, 0, stream>>>(points, cdden);
    rank2_write<<<4096, 256, 0, stream>>>(cdden, (const float4*)uvc,
                                          (float4*)d_out, total_rows);
}

// Round 3
// 228.535 us; speedup vs baseline: 1.0737x; 1.0434x over previous
//
#include <hip/hip_runtime.h>
#include <math.h>

// Problem constants: B=8192, N=49, D=3, D3=42, E=128, K=3
#define N_   49
#define D3_  42
#define E_   128
#define WAVES_PER_BLOCK 4

// ---------------------------------------------------------------------------
// Precompute: collapse feature-pipeline + final matmul to rank-2.
//   out[b,n,e] = cd[b,n]*U[e] + den[b,n]*V[e] + C[e]
// uvc = [U(128) | V(128) | C(128)] f32 in d_ws.
// ---------------------------------------------------------------------------
__global__ void precompute_uvc(const float* __restrict__ W_dist,
                               const float* __restrict__ b_dist,
                               const float* __restrict__ emb,
                               const float* __restrict__ W_den,
                               const float* __restrict__ b_den,
                               const float* __restrict__ W_out,
                               const float* __restrict__ b_out,
                               float* __restrict__ uvc) {
    int e = threadIdx.x;
    if (e >= E_) return;
    const float* embN = emb + N_ * D3_;  // emb[49] row (n_valid == N == 49)
    float u = 0.f, v = 0.f, c = b_out[e];
    for (int j = 0; j < D3_; ++j) {
        float w0 = W_out[j * E_ + e];
        float w1 = W_out[(D3_ + j) * E_ + e];
        float w2 = W_out[(2 * D3_ + j) * E_ + e];
        u = fmaf(W_dist[j], w0, u);
        v = fmaf(W_den[j], w2, v);
        c = fmaf(b_dist[j], w0, c);
        c = fmaf(embN[j], w1, c);
        c = fmaf(b_den[j], w2, c);
    }
    uvc[e]          = u;
    uvc[E_ + e]     = v;
    uvc[2 * E_ + e] = c;
}

// ---------------------------------------------------------------------------
// Fused main kernel: ONE WAVE PER BATCH, no __syncthreads.
//   phase 1: wave stages its 147 pts floats into a private LDS slice
//   phase 2: lanes 0..48 run the centroid+kNN scan (LDS broadcast reads),
//            deposit cd/den into per-wave LDS scratch (same-wave RAW ->
//            lgkmcnt only, no barrier)
//   phase 3: 25 wave-wide float4 store iterations, 1 KiB contiguous each.
// U/V/C global loads are issued at wave start -> in flight during phase 2.
// 2048 blocks x 256 thr = 8 blocks/CU = 32 waves/CU (max occupancy).
// ---------------------------------------------------------------------------
__global__ __launch_bounds__(256) void fused_rank2(
        const float* __restrict__ points,
        const float4* __restrict__ uvc4,
        float4* __restrict__ out4,
        int B) {
    __shared__ float  pts[WAVES_PER_BLOCK][N_ * 3];
    __shared__ float2 cdden[WAVES_PER_BLOCK][N_];

    const int lane = threadIdx.x & 63;
    const int w    = threadIdx.x >> 6;
    const long long b = (long long)blockIdx.x * WAVES_PER_BLOCK + w;
    if (b >= B) return;

    // issue U/V/C loads early; results not needed until phase 3
    const int q = lane & 31;
    const float4 u = uvc4[q];
    const float4 v = uvc4[32 + q];
    const float4 c = uvc4[64 + q];

    // phase 1: stage points
    const float* pb = points + b * (N_ * 3);
    for (int i = lane; i < N_ * 3; i += 64) pts[w][i] = pb[i];
    // same-wave LDS RAW: compiler inserts lgkmcnt wait; no barrier needed

    // phase 2: centroid distance + mean of 3 smallest neighbor distances
    if (lane < N_) {
        const float px = pts[w][3 * lane], py = pts[w][3 * lane + 1],
                    pz = pts[w][3 * lane + 2];
        float sx = 0.f, sy = 0.f, sz = 0.f;
        float s0 = INFINITY, s1 = INFINITY, s2 = INFINITY;
        for (int m = 0; m < N_; ++m) {
            float qx = pts[w][3 * m], qy = pts[w][3 * m + 1], qz = pts[w][3 * m + 2];
            sx += qx; sy += qy; sz += qz;
            float dx = px - qx, dy = py - qy, dz = pz - qz;
            float d2 = fmaf(dx, dx, fmaf(dy, dy, dz * dz));
            if (m != lane) {  // top-3 smallest d2 (monotone vs sqrt -> exact)
                if (d2 < s0)      { s2 = s1; s1 = s0; s0 = d2; }
                else if (d2 < s1) { s2 = s1; s1 = d2; }
                else if (d2 < s2) { s2 = d2; }
            }
        }
        const float inv = 1.0f / (float)N_;
        float cx = sx * inv, cy = sy * inv, cz = sz * inv;
        float dx = px - cx, dy = py - cy, dz = pz - cz;
        float cd  = sqrtf(fmaf(dx, dx, fmaf(dy, dy, dz * dz)));
        float den = (sqrtf(s0) + sqrtf(s1) + sqrtf(s2)) * (1.0f / 3.0f);
        cdden[w][lane] = make_float2(cd, den);
    }

    // phase 3: stream 49*32 = 1568 float4 stores per batch (25 wave-iters)
    float4* ob = out4 + b * (long long)(N_ * 32);
    #pragma unroll 5
    for (int j = 0; j < 25; ++j) {
        int g = j * 64 + lane;          // float4 index within batch
        if (g < N_ * 32) {
            int row = g >> 5;           // 0..48; ds_read broadcast per half-wave
            float2 ad = cdden[w][row];
            float4 r;
            r.x = fmaf(ad.x, u.x, fmaf(ad.y, v.x, c.x));
            r.y = fmaf(ad.x, u.y, fmaf(ad.y, v.y, c.y));
            r.z = fmaf(ad.x, u.z, fmaf(ad.y, v.z, c.z));
            r.w = fmaf(ad.x, u.w, fmaf(ad.y, v.w, c.w));
            ob[g] = r;                  // wave stores 1 KiB contiguous
        }
    }
}

extern "C" void kernel_launch(void* const* d_in, const int* in_sizes, int n_in,
                              void* d_out, int out_size, void* d_ws, size_t ws_size,
                              hipStream_t stream) {
    const float* points = (const float*)d_in[0];
    const float* W_dist = (const float*)d_in[1];
    const float* b_dist = (const float*)d_in[2];
    const float* emb    = (const float*)d_in[3];
    const float* W_den  = (const float*)d_in[4];
    const float* b_den  = (const float*)d_in[5];
    const float* W_out  = (const float*)d_in[6];
    const float* b_out  = (const float*)d_in[7];

    float* uvc = (float*)d_ws;  // 384 f32 = 1536 B scratch

    const int B = in_sizes[0] / (N_ * 3);
    const int nblocks = (B + WAVES_PER_BLOCK - 1) / WAVES_PER_BLOCK;

    precompute_uvc<<<1, 128, 0, stream>>>(W_dist, b_dist, emb, W_den, b_den,
                                          W_out, b_out, uvc);
    fused_rank2<<<nblocks, 64 * WAVES_PER_BLOCK, 0, stream>>>(
        points, (const float4*)uvc, (float4*)d_out, B);
}

// Round 4
// 225.789 us; speedup vs baseline: 1.0868x; 1.0122x over previous
//
#include <hip/hip_runtime.h>
#include <math.h>

// Problem constants: B=8192, N=49, D=3, D3=42, E=128, K=3
#define N_     49
#define D3_    42
#define E_     128
#define WPB    4      // waves per block
#define ROUNDS 2      // batches per wave

// out[b,n,e] = cd[b,n]*U[e] + den[b,n]*V[e] + C[e]   (rank-2 collapse)
//
// Single kernel, one barrier:
//  - threads 0..127 compute U/V/C -> LDS (redundant per block, W_out is
//    21 KB and L2-resident; kills the separate 1-block dispatch)
//  - each wave owns ROUNDS batches; round-1 compute overlaps round-0
//    store drain across waves; round-1 point loads prefetched BEFORE the
//    round-0 store burst so their wait doesn't drain the store queue
//  - cd/den live in registers, broadcast via __shfl in the store loop
//    (no LDS traffic in the store stream)

// kNN + centroid for the batch staged in pts[W]; lanes 0..48 meaningful.
#define KNN(W, CD, DN) do {                                                  \
    const int n = (lane < N_) ? lane : N_ - 1;                               \
    const float px = pts[W][3*n], py = pts[W][3*n+1], pz = pts[W][3*n+2];    \
    float sx = 0.f, sy = 0.f, sz = 0.f;                                      \
    float t0 = INFINITY, t1 = INFINITY, t2 = INFINITY;                       \
    for (int m = 0; m < N_; ++m) {                                           \
        float qx = pts[W][3*m], qy = pts[W][3*m+1], qz = pts[W][3*m+2];      \
        sx += qx; sy += qy; sz += qz;                                        \
        float dx = px - qx, dy = py - qy, dz = pz - qz;                      \
        float d2 = fmaf(dx, dx, fmaf(dy, dy, dz * dz));                      \
        if (m != n) {                                                        \
            if (d2 < t0)      { t2 = t1; t1 = t0; t0 = d2; }                 \
            else if (d2 < t1) { t2 = t1; t1 = d2; }                          \
            else if (d2 < t2) { t2 = d2; }                                   \
        }                                                                    \
    }                                                                        \
    const float inv = 1.0f / (float)N_;                                      \
    float cx = sx*inv, cy = sy*inv, cz = sz*inv;                             \
    float ex = px-cx, ey = py-cy, ez = pz-cz;                                \
    CD = sqrtf(fmaf(ex, ex, fmaf(ey, ey, ez * ez)));                         \
    DN = (sqrtf(t0) + sqrtf(t1) + sqrtf(t2)) * (1.0f / 3.0f);                \
} while (0)

// 25 wave-wide float4 store iterations (1 KiB contiguous each); row value
// broadcast from the owning lane via shuffle.
#define STORES(BB, CD, DN) do {                                              \
    float4* ob = out4 + (long long)(BB) * (N_ * 32);                         \
    _Pragma("unroll")                                                        \
    for (int j = 0; j < 25; ++j) {                                           \
        int row = 2*j + (lane >> 5);                                         \
        float a = __shfl(CD, row);                                           \
        float d = __shfl(DN, row);                                           \
        if (row < N_) {                                                      \
            float4 r;                                                        \
            r.x = fmaf(a, u4.x, fmaf(d, v4.x, c4.x));                        \
            r.y = fmaf(a, u4.y, fmaf(d, v4.y, c4.y));                        \
            r.z = fmaf(a, u4.z, fmaf(d, v4.z, c4.z));                        \
            r.w = fmaf(a, u4.w, fmaf(d, v4.w, c4.w));                        \
            ob[row * 32 + q] = r;                                            \
        }                                                                    \
    }                                                                        \
} while (0)

__global__ __launch_bounds__(256) void fused_all(
        const float* __restrict__ points,
        const float* __restrict__ W_dist,
        const float* __restrict__ b_dist,
        const float* __restrict__ emb,
        const float* __restrict__ W_den,
        const float* __restrict__ b_den,
        const float* __restrict__ W_out,
        const float* __restrict__ b_out,
        float4* __restrict__ out4,
        int B) {
    __shared__ float pts[WPB][N_ * 3];
    __shared__ __align__(16) float sUVC[3 * E_];

    const int tid    = threadIdx.x;
    const int lane   = tid & 63;
    const int w      = tid >> 6;
    const int nwaves = gridDim.x * WPB;
    const int wid    = blockIdx.x * WPB + w;

    // ---- round-0 point loads: issue first so they're in flight ----
    const long long b0 = wid;
    const bool v0 = (b0 < B);
    float s0a = 0.f, s0b = 0.f, s0c = 0.f;
    if (v0) {
        const float* pb = points + b0 * (N_ * 3);
        s0a = pb[lane];
        s0b = pb[64 + lane];
        if (lane < N_ * 3 - 128) s0c = pb[128 + lane];
    }

    // ---- rank-2 collapse: threads 0..127 compute U/V/C into LDS ----
    if (tid < E_) {
        const float* embN = emb + N_ * D3_;  // emb[49] (n_valid == N == 49)
        float u = 0.f, vv = 0.f, c = b_out[tid];
        for (int j = 0; j < D3_; ++j) {
            float w0 = W_out[j * E_ + tid];
            float w1 = W_out[(D3_ + j) * E_ + tid];
            float w2 = W_out[(2 * D3_ + j) * E_ + tid];
            u  = fmaf(W_dist[j], w0, u);
            vv = fmaf(W_den[j],  w2, vv);
            c  = fmaf(b_dist[j], w0, c);
            c  = fmaf(embN[j],   w1, c);
            c  = fmaf(b_den[j],  w2, c);
        }
        sUVC[tid]          = u;
        sUVC[E_ + tid]     = vv;
        sUVC[2 * E_ + tid] = c;
    }

    // ---- stage round-0 points into this wave's LDS slice ----
    if (v0) {
        pts[w][lane]      = s0a;
        pts[w][64 + lane] = s0b;
        if (lane < N_ * 3 - 128) pts[w][128 + lane] = s0c;
    }

    // ---- prefetch round-1 points (in flight during kNN + stores-0) ----
    const long long b1 = (long long)wid + nwaves;
    const bool v1 = (b1 < B);
    float s1a = 0.f, s1b = 0.f, s1c = 0.f;
    if (v1) {
        const float* pb = points + b1 * (N_ * 3);
        s1a = pb[lane];
        s1b = pb[64 + lane];
        if (lane < N_ * 3 - 128) s1c = pb[128 + lane];
    }

    // ---- kNN round 0 (same-wave LDS RAW -> lgkmcnt only) ----
    float cd0 = 0.f, dn0 = 0.f;
    if (v0) { KNN(w, cd0, dn0); }

    // ---- one barrier: U/V/C visibility ----
    __syncthreads();
    const int q = lane & 31;
    const float4 u4 = *(const float4*)&sUVC[4 * q];           // 2-way alias:
    const float4 v4 = *(const float4*)&sUVC[E_ + 4 * q];      // broadcast, free
    const float4 c4 = *(const float4*)&sUVC[2 * E_ + 4 * q];

    // ---- store round 0 ----
    if (v0) { STORES(b0, cd0, dn0); }

    // ---- round 1: re-stage (per-wave DS ops are in order), kNN, store ----
    if (v1) {
        pts[w][lane]      = s1a;
        pts[w][64 + lane] = s1b;
        if (lane < N_ * 3 - 128) pts[w][128 + lane] = s1c;
        float cd1, dn1;
        KNN(w, cd1, dn1);
        STORES(b1, cd1, dn1);
    }
}

extern "C" void kernel_launch(void* const* d_in, const int* in_sizes, int n_in,
                              void* d_out, int out_size, void* d_ws, size_t ws_size,
                              hipStream_t stream) {
    const float* points = (const float*)d_in[0];
    const float* W_dist = (const float*)d_in[1];
    const float* b_dist = (const float*)d_in[2];
    const float* emb    = (const float*)d_in[3];
    const float* W_den  = (const float*)d_in[4];
    const float* b_den  = (const float*)d_in[5];
    const float* W_out  = (const float*)d_in[6];
    const float* b_out  = (const float*)d_in[7];

    const int B = in_sizes[0] / (N_ * 3);
    const int nblocks = (B + WPB * ROUNDS - 1) / (WPB * ROUNDS);  // 1024 for B=8192

    fused_all<<<nblocks, 64 * WPB, 0, stream>>>(
        points, W_dist, b_dist, emb, W_den, b_den, W_out, b_out,
        (float4*)d_out, B);
}